// Round 3
// baseline (549.425 us; speedup 1.0000x reference)
//
#include <hip/hip_runtime.h>

#define NN 50000
#define NE 800000
#define D 128
#define NCLS 47
#define ZPAD 64   // padded width for projected layer-2 features
#define LN_EPS 1e-5f

// ---------------- CSR build ----------------
__global__ void k_count(const int* __restrict__ dst, int* __restrict__ counts) {
  int i = blockIdx.x * blockDim.x + threadIdx.x;
  if (i < NE) atomicAdd(&counts[dst[i]], 1);
}

__global__ void k_scan1(const int* __restrict__ counts, int* __restrict__ excl,
                        int* __restrict__ bsum) {
  __shared__ int tmp[256];
  int t = threadIdx.x, i = blockIdx.x * 256 + t;
  int v = (i < NN) ? counts[i] : 0;
  tmp[t] = v;
  __syncthreads();
  for (int off = 1; off < 256; off <<= 1) {
    int u = (t >= off) ? tmp[t - off] : 0;
    __syncthreads();
    tmp[t] += u;
    __syncthreads();
  }
  if (i < NN) excl[i] = tmp[t] - v;
  if (t == 255) bsum[blockIdx.x] = tmp[255];
}

__global__ void k_scan2(int* __restrict__ bsum, int nb) {
  __shared__ int tmp[256];
  int t = threadIdx.x;
  int v = (t < nb) ? bsum[t] : 0;
  tmp[t] = v;
  __syncthreads();
  for (int off = 1; off < 256; off <<= 1) {
    int u = (t >= off) ? tmp[t - off] : 0;
    __syncthreads();
    tmp[t] += u;
    __syncthreads();
  }
  if (t < nb) bsum[t] = tmp[t] - v;
}

__global__ void k_scan3(int* __restrict__ indptr, const int* __restrict__ bsum,
                        int* __restrict__ cursor) {
  int i = blockIdx.x * 256 + threadIdx.x;
  if (i < NN) {
    int v = indptr[i] + bsum[i >> 8];
    indptr[i] = v;
    cursor[i] = v;
  }
  if (i == 0) indptr[NN] = NE;
}

__global__ void k_scatter(const int* __restrict__ src, const int* __restrict__ dst,
                          int* __restrict__ cursor, int* __restrict__ esrc) {
  int i = blockIdx.x * blockDim.x + threadIdx.x;
  if (i < NE) {
    int d = dst[i];
    int pos = atomicAdd(&cursor[d], 1);
    esrc[pos] = src[i];
  }
}

// ---------------- mean aggregation (128-wide): one wave per node ----------------
__global__ __launch_bounds__(256) void k_agg(const float* __restrict__ feat,
                                             const int* __restrict__ indptr,
                                             const int* __restrict__ esrc,
                                             float* __restrict__ out) {
  int w = (blockIdx.x * 256 + threadIdx.x) >> 6;
  int lane = threadIdx.x & 63;
  if (w >= NN) return;
  int beg = indptr[w], end = indptr[w + 1];
  float a0 = 0.f, a1 = 0.f;
  int e = beg;
  for (; e + 3 < end; e += 4) {  // 4 independent gather chains
    int s0 = esrc[e], s1 = esrc[e + 1], s2 = esrc[e + 2], s3 = esrc[e + 3];
    float2 v0 = *(const float2*)(feat + (size_t)s0 * D + lane * 2);
    float2 v1 = *(const float2*)(feat + (size_t)s1 * D + lane * 2);
    float2 v2 = *(const float2*)(feat + (size_t)s2 * D + lane * 2);
    float2 v3 = *(const float2*)(feat + (size_t)s3 * D + lane * 2);
    a0 += v0.x + v1.x + v2.x + v3.x;
    a1 += v0.y + v1.y + v2.y + v3.y;
  }
  for (; e < end; ++e) {
    int s0 = esrc[e];
    float2 v0 = *(const float2*)(feat + (size_t)s0 * D + lane * 2);
    a0 += v0.x;
    a1 += v0.y;
  }
  float inv = 1.0f / fmaxf((float)(end - beg), 1.0f);
  float2 o;
  o.x = a0 * inv;
  o.y = a1 * inv;
  *(float2*)(out + (size_t)w * D + lane * 2) = o;
}

// ---------------- fused dual-GEMM + LN + ReLU (hidden layers) ----------------
// 256 thr (4 waves), 64 rows/block, wave handles 16 rows, lane j -> cols j, j+64.
__global__ __launch_bounds__(256) void k_gemm_ln(
    const float* __restrict__ h, const float* __restrict__ hn,
    const float* __restrict__ ws, const float* __restrict__ wn,
    const float* __restrict__ b, const float* __restrict__ g,
    const float* __restrict__ be, float* __restrict__ out) {
  __shared__ float lds[64][256];  // cols [0,128)=h, [128,256)=hn (64 KB)
  int tid = threadIdx.x;
  int row0 = blockIdx.x * 64;
  for (int i = tid; i < 64 * 64; i += 256) {  // float4 granules
    int r = i >> 6, q = i & 63;
    int row = row0 + r;
    float4 v = make_float4(0.f, 0.f, 0.f, 0.f);
    if (row < NN) {
      const float* p = (q < 32) ? (h + (size_t)row * D + q * 4)
                                : (hn + (size_t)row * D + (q - 32) * 4);
      v = *(const float4*)p;
    }
    *(float4*)&lds[r][q * 4] = v;
  }
  __syncthreads();

  int wv = tid >> 6, lane = tid & 63;
  int rbase = wv * 16;
  float acc0[16], acc1[16];
#pragma unroll
  for (int r = 0; r < 16; ++r) { acc0[r] = 0.f; acc1[r] = 0.f; }

  for (int k = 0; k < 128; k += 4) {  // self
    float w00 = ws[(k + 0) * 128 + lane], w01 = ws[(k + 0) * 128 + lane + 64];
    float w10 = ws[(k + 1) * 128 + lane], w11 = ws[(k + 1) * 128 + lane + 64];
    float w20 = ws[(k + 2) * 128 + lane], w21 = ws[(k + 2) * 128 + lane + 64];
    float w30 = ws[(k + 3) * 128 + lane], w31 = ws[(k + 3) * 128 + lane + 64];
#pragma unroll
    for (int r = 0; r < 16; ++r) {
      float4 hv = *(const float4*)&lds[rbase + r][k];  // b128 broadcast
      acc0[r] = fmaf(hv.x, w00, acc0[r]);
      acc1[r] = fmaf(hv.x, w01, acc1[r]);
      acc0[r] = fmaf(hv.y, w10, acc0[r]);
      acc1[r] = fmaf(hv.y, w11, acc1[r]);
      acc0[r] = fmaf(hv.z, w20, acc0[r]);
      acc1[r] = fmaf(hv.z, w21, acc1[r]);
      acc0[r] = fmaf(hv.w, w30, acc0[r]);
      acc1[r] = fmaf(hv.w, w31, acc1[r]);
    }
  }
  for (int k = 0; k < 128; k += 4) {  // neigh
    float w00 = wn[(k + 0) * 128 + lane], w01 = wn[(k + 0) * 128 + lane + 64];
    float w10 = wn[(k + 1) * 128 + lane], w11 = wn[(k + 1) * 128 + lane + 64];
    float w20 = wn[(k + 2) * 128 + lane], w21 = wn[(k + 2) * 128 + lane + 64];
    float w30 = wn[(k + 3) * 128 + lane], w31 = wn[(k + 3) * 128 + lane + 64];
#pragma unroll
    for (int r = 0; r < 16; ++r) {
      float4 hv = *(const float4*)&lds[rbase + r][128 + k];
      acc0[r] = fmaf(hv.x, w00, acc0[r]);
      acc1[r] = fmaf(hv.x, w01, acc1[r]);
      acc0[r] = fmaf(hv.y, w10, acc0[r]);
      acc1[r] = fmaf(hv.y, w11, acc1[r]);
      acc0[r] = fmaf(hv.z, w20, acc0[r]);
      acc1[r] = fmaf(hv.z, w21, acc1[r]);
      acc0[r] = fmaf(hv.w, w30, acc0[r]);
      acc1[r] = fmaf(hv.w, w31, acc1[r]);
    }
  }

  float bj0 = b[lane], bj1 = b[lane + 64];
  float gj0 = g[lane], gj1 = g[lane + 64];
  float ej0 = be[lane], ej1 = be[lane + 64];
#pragma unroll
  for (int r = 0; r < 16; ++r) {
    float v0 = acc0[r] + bj0, v1 = acc1[r] + bj1;
    float s = v0 + v1, q2 = v0 * v0 + v1 * v1;
#pragma unroll
    for (int off = 1; off < 64; off <<= 1) {
      s += __shfl_xor(s, off, 64);
      q2 += __shfl_xor(q2, off, 64);
    }
    float mu = s * (1.0f / 128.0f);
    float var = q2 * (1.0f / 128.0f) - mu * mu;
    float rs = rsqrtf(var + LN_EPS);
    float o0 = fmaxf((v0 - mu) * rs * gj0 + ej0, 0.f);
    float o1 = fmaxf((v1 - mu) * rs * gj1 + ej1, 0.f);
    int row = row0 + rbase + r;
    if (row < NN) {
      out[(size_t)row * D + lane] = o0;
      out[(size_t)row * D + lane + 64] = o1;
    }
  }
}

// ---------------- layer 2: project h2 through BOTH weight matrices ----------------
// s2p[row][j] = (h2 @ w_self2)[row][j] + b2[j]   (j < 47)
// z2 [row][j] = (h2 @ w_neigh2)[row][j]          (j < 47; cols 47..63 zeroed)
__global__ __launch_bounds__(256) void k_gemm_proj2(
    const float* __restrict__ h, const float* __restrict__ ws,
    const float* __restrict__ wn, const float* __restrict__ b,
    float* __restrict__ s2p, float* __restrict__ z2) {
  __shared__ float lds[64][128];  // 32 KB
  int tid = threadIdx.x;
  int row0 = blockIdx.x * 64;
  for (int i = tid; i < 64 * 32; i += 256) {  // float4 granules, 32 per row
    int r = i >> 5, q = i & 31;
    int row = row0 + r;
    float4 v = make_float4(0.f, 0.f, 0.f, 0.f);
    if (row < NN) v = *(const float4*)(h + (size_t)row * D + q * 4);
    *(float4*)&lds[r][q * 4] = v;
  }
  __syncthreads();

  int wv = tid >> 6, lane = tid & 63;
  int rbase = wv * 16;
  bool act = lane < NCLS;
  float accS[16], accZ[16];
#pragma unroll
  for (int r = 0; r < 16; ++r) { accS[r] = 0.f; accZ[r] = 0.f; }

  for (int k = 0; k < 128; k += 4) {
    float ws0 = act ? ws[(k + 0) * NCLS + lane] : 0.f;
    float ws1 = act ? ws[(k + 1) * NCLS + lane] : 0.f;
    float ws2 = act ? ws[(k + 2) * NCLS + lane] : 0.f;
    float ws3 = act ? ws[(k + 3) * NCLS + lane] : 0.f;
    float wn0 = act ? wn[(k + 0) * NCLS + lane] : 0.f;
    float wn1 = act ? wn[(k + 1) * NCLS + lane] : 0.f;
    float wn2 = act ? wn[(k + 2) * NCLS + lane] : 0.f;
    float wn3 = act ? wn[(k + 3) * NCLS + lane] : 0.f;
#pragma unroll
    for (int r = 0; r < 16; ++r) {
      float4 hv = *(const float4*)&lds[rbase + r][k];
      accS[r] = fmaf(hv.x, ws0, accS[r]);
      accZ[r] = fmaf(hv.x, wn0, accZ[r]);
      accS[r] = fmaf(hv.y, ws1, accS[r]);
      accZ[r] = fmaf(hv.y, wn1, accZ[r]);
      accS[r] = fmaf(hv.z, ws2, accS[r]);
      accZ[r] = fmaf(hv.z, wn2, accZ[r]);
      accS[r] = fmaf(hv.w, ws3, accS[r]);
      accZ[r] = fmaf(hv.w, wn3, accZ[r]);
    }
  }

  float bj = act ? b[lane] : 0.f;
#pragma unroll
  for (int r = 0; r < 16; ++r) {
    int row = row0 + rbase + r;
    if (row < NN) {
      // all 64 lanes write z2 so the pad cols are ZERO (gather reads them)
      z2[(size_t)row * ZPAD + lane] = act ? accZ[r] : 0.f;
      s2p[(size_t)row * ZPAD + lane] = accS[r] + bj;  // pad lanes never read
    }
  }
}

// ---------------- layer 2 final: out = s2p + mean_neigh(z2) ----------------
__global__ __launch_bounds__(256) void k_agg2(const float* __restrict__ z2,
                                              const float* __restrict__ s2p,
                                              const int* __restrict__ indptr,
                                              const int* __restrict__ esrc,
                                              float* __restrict__ out) {
  int w = (blockIdx.x * 256 + threadIdx.x) >> 6;
  int lane = threadIdx.x & 63;
  if (w >= NN) return;
  int beg = indptr[w], end = indptr[w + 1];
  float a = 0.f;
  int e = beg;
  for (; e + 3 < end; e += 4) {
    int s0 = esrc[e], s1 = esrc[e + 1], s2 = esrc[e + 2], s3 = esrc[e + 3];
    float v0 = z2[(size_t)s0 * ZPAD + lane];
    float v1 = z2[(size_t)s1 * ZPAD + lane];
    float v2 = z2[(size_t)s2 * ZPAD + lane];
    float v3 = z2[(size_t)s3 * ZPAD + lane];
    a += v0 + v1 + v2 + v3;
  }
  for (; e < end; ++e) a += z2[(size_t)esrc[e] * ZPAD + lane];
  float inv = 1.0f / fmaxf((float)(end - beg), 1.0f);
  if (lane < NCLS)
    out[(size_t)w * NCLS + lane] = s2p[(size_t)w * ZPAD + lane] + a * inv;
}

// ---------------- launch ----------------
extern "C" void kernel_launch(void* const* d_in, const int* in_sizes, int n_in,
                              void* d_out, int out_size, void* d_ws, size_t ws_size,
                              hipStream_t stream) {
  (void)in_sizes; (void)n_in; (void)out_size; (void)ws_size;
  const float* x       = (const float*)d_in[0];
  const int*   src     = (const int*)d_in[1];
  const int*   dst     = (const int*)d_in[2];
  const float* w_self0 = (const float*)d_in[3];
  const float* w_nei0  = (const float*)d_in[4];
  const float* b0      = (const float*)d_in[5];
  const float* g0      = (const float*)d_in[6];
  const float* be0     = (const float*)d_in[7];
  const float* w_self1 = (const float*)d_in[8];
  const float* w_nei1  = (const float*)d_in[9];
  const float* b1      = (const float*)d_in[10];
  const float* g1      = (const float*)d_in[11];
  const float* be1     = (const float*)d_in[12];
  const float* w_self2 = (const float*)d_in[13];
  const float* w_nei2  = (const float*)d_in[14];
  const float* b2      = (const float*)d_in[15];
  float* outp = (float*)d_out;

  char* ws = (char*)d_ws;
  size_t off = 0;
  auto alloc = [&](size_t bytes) -> void* {
    off = (off + 255) & ~(size_t)255;
    void* p = ws + off;
    off += bytes;
    return p;
  };
  int*   counts = (int*)alloc(NN * sizeof(int));
  int*   indptr = (int*)alloc((NN + 1) * sizeof(int));
  int*   cursor = (int*)alloc(NN * sizeof(int));
  int*   bsum   = (int*)alloc(256 * sizeof(int));
  int*   esrc   = (int*)alloc(NE * sizeof(int));
  float* hn     = (float*)alloc((size_t)NN * D * sizeof(float));  // also z2 (layer 2)
  float* h1     = (float*)alloc((size_t)NN * D * sizeof(float));  // also s2p (layer 2)
  float* h2     = (float*)alloc((size_t)NN * D * sizeof(float));
  float* z2  = hn;  // 12.8 MB into 25.6 MB slot
  float* s2p = h1;  // h1 dead once h2 exists

  const int nbScan = (NN + 255) / 256;  // 196

  // CSR build
  hipMemsetAsync(counts, 0, NN * sizeof(int), stream);
  k_count<<<(NE + 255) / 256, 256, 0, stream>>>(dst, counts);
  k_scan1<<<nbScan, 256, 0, stream>>>(counts, indptr, bsum);
  k_scan2<<<1, 256, 0, stream>>>(bsum, nbScan);
  k_scan3<<<nbScan, 256, 0, stream>>>(indptr, bsum, cursor);
  k_scatter<<<(NE + 255) / 256, 256, 0, stream>>>(src, dst, cursor, esrc);

  const int aggBlocks  = (NN * 64) / 256;  // 12500
  const int gemmBlocks = (NN + 63) / 64;   // 782

  // layer 0
  k_agg<<<aggBlocks, 256, 0, stream>>>(x, indptr, esrc, hn);
  k_gemm_ln<<<gemmBlocks, 256, 0, stream>>>(x, hn, w_self0, w_nei0, b0, g0, be0, h1);
  // layer 1
  k_agg<<<aggBlocks, 256, 0, stream>>>(h1, indptr, esrc, hn);
  k_gemm_ln<<<gemmBlocks, 256, 0, stream>>>(h1, hn, w_self1, w_nei1, b1, g1, be1, h2);
  // layer 2: project first (agg commutes with the linear map), then 64-wide agg
  k_gemm_proj2<<<gemmBlocks, 256, 0, stream>>>(h2, w_self2, w_nei2, b2, s2p, z2);
  k_agg2<<<aggBlocks, 256, 0, stream>>>(z2, s2p, indptr, esrc, outp);
}

// Round 4
// 529.965 us; speedup vs baseline: 1.0367x; 1.0367x over previous
//
#include <hip/hip_runtime.h>

#define NN 50000
#define NE 800000
#define D 128
#define NCLS 47
#define ZPAD 64   // padded width for projected layer-2 features
#define LN_EPS 1e-5f

// ---------------- CSR build ----------------
__global__ void k_count(const int* __restrict__ dst, int* __restrict__ counts) {
  int i = blockIdx.x * blockDim.x + threadIdx.x;
  if (i < NE) atomicAdd(&counts[dst[i]], 1);
}

__global__ void k_scan1(const int* __restrict__ counts, int* __restrict__ excl,
                        int* __restrict__ bsum) {
  __shared__ int tmp[256];
  int t = threadIdx.x, i = blockIdx.x * 256 + t;
  int v = (i < NN) ? counts[i] : 0;
  tmp[t] = v;
  __syncthreads();
  for (int off = 1; off < 256; off <<= 1) {
    int u = (t >= off) ? tmp[t - off] : 0;
    __syncthreads();
    tmp[t] += u;
    __syncthreads();
  }
  if (i < NN) excl[i] = tmp[t] - v;
  if (t == 255) bsum[blockIdx.x] = tmp[255];
}

__global__ void k_scan2(int* __restrict__ bsum, int nb) {
  __shared__ int tmp[256];
  int t = threadIdx.x;
  int v = (t < nb) ? bsum[t] : 0;
  tmp[t] = v;
  __syncthreads();
  for (int off = 1; off < 256; off <<= 1) {
    int u = (t >= off) ? tmp[t - off] : 0;
    __syncthreads();
    tmp[t] += u;
    __syncthreads();
  }
  if (t < nb) bsum[t] = tmp[t] - v;
}

__global__ void k_scan3(int* __restrict__ indptr, const int* __restrict__ bsum,
                        int* __restrict__ cursor) {
  int i = blockIdx.x * 256 + threadIdx.x;
  if (i < NN) {
    int v = indptr[i] + bsum[i >> 8];
    indptr[i] = v;
    cursor[i] = v;
  }
  if (i == 0) indptr[NN] = NE;
}

__global__ void k_scatter(const int* __restrict__ src, const int* __restrict__ dst,
                          int* __restrict__ cursor, int* __restrict__ esrc) {
  int i = blockIdx.x * blockDim.x + threadIdx.x;
  if (i < NE) {
    int d = dst[i];
    int pos = atomicAdd(&cursor[d], 1);
    esrc[pos] = src[i];
  }
}

// ---------------- mean aggregation (128-wide): one wave per node, 8 chains ----------------
__global__ __launch_bounds__(256) void k_agg(const float* __restrict__ feat,
                                             const int* __restrict__ indptr,
                                             const int* __restrict__ esrc,
                                             float* __restrict__ out) {
  int w = (blockIdx.x * 256 + threadIdx.x) >> 6;
  int lane = threadIdx.x & 63;
  if (w >= NN) return;
  int beg = indptr[w], end = indptr[w + 1];
  float a0 = 0.f, a1 = 0.f;
  int e = beg;
  for (; e + 7 < end; e += 8) {  // 8 independent gather chains in flight
    int s0 = esrc[e],     s1 = esrc[e + 1], s2 = esrc[e + 2], s3 = esrc[e + 3];
    int s4 = esrc[e + 4], s5 = esrc[e + 5], s6 = esrc[e + 6], s7 = esrc[e + 7];
    float2 v0 = *(const float2*)(feat + (size_t)s0 * D + lane * 2);
    float2 v1 = *(const float2*)(feat + (size_t)s1 * D + lane * 2);
    float2 v2 = *(const float2*)(feat + (size_t)s2 * D + lane * 2);
    float2 v3 = *(const float2*)(feat + (size_t)s3 * D + lane * 2);
    float2 v4 = *(const float2*)(feat + (size_t)s4 * D + lane * 2);
    float2 v5 = *(const float2*)(feat + (size_t)s5 * D + lane * 2);
    float2 v6 = *(const float2*)(feat + (size_t)s6 * D + lane * 2);
    float2 v7 = *(const float2*)(feat + (size_t)s7 * D + lane * 2);
    a0 += v0.x + v1.x + v2.x + v3.x + v4.x + v5.x + v6.x + v7.x;
    a1 += v0.y + v1.y + v2.y + v3.y + v4.y + v5.y + v6.y + v7.y;
  }
  for (; e + 1 < end; e += 2) {
    int s0 = esrc[e], s1 = esrc[e + 1];
    float2 v0 = *(const float2*)(feat + (size_t)s0 * D + lane * 2);
    float2 v1 = *(const float2*)(feat + (size_t)s1 * D + lane * 2);
    a0 += v0.x + v1.x;
    a1 += v0.y + v1.y;
  }
  if (e < end) {
    float2 v0 = *(const float2*)(feat + (size_t)esrc[e] * D + lane * 2);
    a0 += v0.x;
    a1 += v0.y;
  }
  float inv = 1.0f / fmaxf((float)(end - beg), 1.0f);
  float2 o;
  o.x = a0 * inv;
  o.y = a1 * inv;
  *(float2*)(out + (size_t)w * D + lane * 2) = o;
}

// ---------------- fused dual-GEMM + LN + ReLU (hidden layers) ----------------
// 32 rows/block (32 KB LDS -> 5 blocks/CU), 256 thr (4 waves), wave handles 8 rows,
// lane j owns output cols j and j+64.
__global__ __launch_bounds__(256, 5) void k_gemm_ln(
    const float* __restrict__ h, const float* __restrict__ hn,
    const float* __restrict__ ws, const float* __restrict__ wn,
    const float* __restrict__ b, const float* __restrict__ g,
    const float* __restrict__ be, float* __restrict__ out) {
  __shared__ float lds[32][256];  // cols [0,128)=h, [128,256)=hn (32 KB)
  int tid = threadIdx.x;
  int row0 = blockIdx.x * 32;
  for (int i = tid; i < 32 * 64; i += 256) {  // float4 granules, 64 per row
    int r = i >> 6, q = i & 63;
    int row = row0 + r;
    float4 v = make_float4(0.f, 0.f, 0.f, 0.f);
    if (row < NN) {
      const float* p = (q < 32) ? (h + (size_t)row * D + q * 4)
                                : (hn + (size_t)row * D + (q - 32) * 4);
      v = *(const float4*)p;
    }
    *(float4*)&lds[r][q * 4] = v;
  }
  __syncthreads();

  int wv = tid >> 6, lane = tid & 63;
  int rbase = wv * 8;
  float acc0[8], acc1[8];
#pragma unroll
  for (int r = 0; r < 8; ++r) { acc0[r] = 0.f; acc1[r] = 0.f; }

  for (int k = 0; k < 128; k += 4) {  // self
    float w00 = ws[(k + 0) * 128 + lane], w01 = ws[(k + 0) * 128 + lane + 64];
    float w10 = ws[(k + 1) * 128 + lane], w11 = ws[(k + 1) * 128 + lane + 64];
    float w20 = ws[(k + 2) * 128 + lane], w21 = ws[(k + 2) * 128 + lane + 64];
    float w30 = ws[(k + 3) * 128 + lane], w31 = ws[(k + 3) * 128 + lane + 64];
#pragma unroll
    for (int r = 0; r < 8; ++r) {
      float4 hv = *(const float4*)&lds[rbase + r][k];  // b128 broadcast
      acc0[r] = fmaf(hv.x, w00, acc0[r]);
      acc1[r] = fmaf(hv.x, w01, acc1[r]);
      acc0[r] = fmaf(hv.y, w10, acc0[r]);
      acc1[r] = fmaf(hv.y, w11, acc1[r]);
      acc0[r] = fmaf(hv.z, w20, acc0[r]);
      acc1[r] = fmaf(hv.z, w21, acc1[r]);
      acc0[r] = fmaf(hv.w, w30, acc0[r]);
      acc1[r] = fmaf(hv.w, w31, acc1[r]);
    }
  }
  for (int k = 0; k < 128; k += 4) {  // neigh
    float w00 = wn[(k + 0) * 128 + lane], w01 = wn[(k + 0) * 128 + lane + 64];
    float w10 = wn[(k + 1) * 128 + lane], w11 = wn[(k + 1) * 128 + lane + 64];
    float w20 = wn[(k + 2) * 128 + lane], w21 = wn[(k + 2) * 128 + lane + 64];
    float w30 = wn[(k + 3) * 128 + lane], w31 = wn[(k + 3) * 128 + lane + 64];
#pragma unroll
    for (int r = 0; r < 8; ++r) {
      float4 hv = *(const float4*)&lds[rbase + r][128 + k];
      acc0[r] = fmaf(hv.x, w00, acc0[r]);
      acc1[r] = fmaf(hv.x, w01, acc1[r]);
      acc0[r] = fmaf(hv.y, w10, acc0[r]);
      acc1[r] = fmaf(hv.y, w11, acc1[r]);
      acc0[r] = fmaf(hv.z, w20, acc0[r]);
      acc1[r] = fmaf(hv.z, w21, acc1[r]);
      acc0[r] = fmaf(hv.w, w30, acc0[r]);
      acc1[r] = fmaf(hv.w, w31, acc1[r]);
    }
  }

  float bj0 = b[lane], bj1 = b[lane + 64];
  float gj0 = g[lane], gj1 = g[lane + 64];
  float ej0 = be[lane], ej1 = be[lane + 64];
#pragma unroll
  for (int r = 0; r < 8; ++r) {
    float v0 = acc0[r] + bj0, v1 = acc1[r] + bj1;
    float s = v0 + v1, q2 = v0 * v0 + v1 * v1;
#pragma unroll
    for (int off = 1; off < 64; off <<= 1) {
      s += __shfl_xor(s, off, 64);
      q2 += __shfl_xor(q2, off, 64);
    }
    float mu = s * (1.0f / 128.0f);
    float var = q2 * (1.0f / 128.0f) - mu * mu;
    float rs = rsqrtf(var + LN_EPS);
    float o0 = fmaxf((v0 - mu) * rs * gj0 + ej0, 0.f);
    float o1 = fmaxf((v1 - mu) * rs * gj1 + ej1, 0.f);
    int row = row0 + rbase + r;
    if (row < NN) {
      out[(size_t)row * D + lane] = o0;
      out[(size_t)row * D + lane + 64] = o1;
    }
  }
}

// ---------------- layer 2: project h2 through BOTH weight matrices ----------------
// s2p[row][j] = (h2 @ w_self2)[row][j] + b2[j]   (j < 47)
// z2 [row][j] = (h2 @ w_neigh2)[row][j]          (j < 47; cols 47..63 zeroed)
__global__ __launch_bounds__(256) void k_gemm_proj2(
    const float* __restrict__ h, const float* __restrict__ ws,
    const float* __restrict__ wn, const float* __restrict__ b,
    float* __restrict__ s2p, float* __restrict__ z2) {
  __shared__ float lds[32][128];  // 16 KB
  int tid = threadIdx.x;
  int row0 = blockIdx.x * 32;
  for (int i = tid; i < 32 * 32; i += 256) {  // float4 granules, 32 per row
    int r = i >> 5, q = i & 31;
    int row = row0 + r;
    float4 v = make_float4(0.f, 0.f, 0.f, 0.f);
    if (row < NN) v = *(const float4*)(h + (size_t)row * D + q * 4);
    *(float4*)&lds[r][q * 4] = v;
  }
  __syncthreads();

  int wv = tid >> 6, lane = tid & 63;
  int rbase = wv * 8;
  bool act = lane < NCLS;
  float accS[8], accZ[8];
#pragma unroll
  for (int r = 0; r < 8; ++r) { accS[r] = 0.f; accZ[r] = 0.f; }

  for (int k = 0; k < 128; k += 4) {
    float ws0 = act ? ws[(k + 0) * NCLS + lane] : 0.f;
    float ws1 = act ? ws[(k + 1) * NCLS + lane] : 0.f;
    float ws2 = act ? ws[(k + 2) * NCLS + lane] : 0.f;
    float ws3 = act ? ws[(k + 3) * NCLS + lane] : 0.f;
    float wn0 = act ? wn[(k + 0) * NCLS + lane] : 0.f;
    float wn1 = act ? wn[(k + 1) * NCLS + lane] : 0.f;
    float wn2 = act ? wn[(k + 2) * NCLS + lane] : 0.f;
    float wn3 = act ? wn[(k + 3) * NCLS + lane] : 0.f;
#pragma unroll
    for (int r = 0; r < 8; ++r) {
      float4 hv = *(const float4*)&lds[rbase + r][k];
      accS[r] = fmaf(hv.x, ws0, accS[r]);
      accZ[r] = fmaf(hv.x, wn0, accZ[r]);
      accS[r] = fmaf(hv.y, ws1, accS[r]);
      accZ[r] = fmaf(hv.y, wn1, accZ[r]);
      accS[r] = fmaf(hv.z, ws2, accS[r]);
      accZ[r] = fmaf(hv.z, wn2, accZ[r]);
      accS[r] = fmaf(hv.w, ws3, accS[r]);
      accZ[r] = fmaf(hv.w, wn3, accZ[r]);
    }
  }

  float bj = act ? b[lane] : 0.f;
#pragma unroll
  for (int r = 0; r < 8; ++r) {
    int row = row0 + rbase + r;
    if (row < NN) {
      // all 64 lanes write z2 so the pad cols are ZERO (gather reads them)
      z2[(size_t)row * ZPAD + lane] = act ? accZ[r] : 0.f;
      s2p[(size_t)row * ZPAD + lane] = accS[r] + bj;  // pad lanes never read
    }
  }
}

// ---------------- layer 2 final: out = s2p + mean_neigh(z2) ----------------
__global__ __launch_bounds__(256) void k_agg2(const float* __restrict__ z2,
                                              const float* __restrict__ s2p,
                                              const int* __restrict__ indptr,
                                              const int* __restrict__ esrc,
                                              float* __restrict__ out) {
  int w = (blockIdx.x * 256 + threadIdx.x) >> 6;
  int lane = threadIdx.x & 63;
  if (w >= NN) return;
  int beg = indptr[w], end = indptr[w + 1];
  float a = 0.f;
  int e = beg;
  for (; e + 7 < end; e += 8) {
    int s0 = esrc[e],     s1 = esrc[e + 1], s2 = esrc[e + 2], s3 = esrc[e + 3];
    int s4 = esrc[e + 4], s5 = esrc[e + 5], s6 = esrc[e + 6], s7 = esrc[e + 7];
    a += z2[(size_t)s0 * ZPAD + lane] + z2[(size_t)s1 * ZPAD + lane] +
         z2[(size_t)s2 * ZPAD + lane] + z2[(size_t)s3 * ZPAD + lane] +
         z2[(size_t)s4 * ZPAD + lane] + z2[(size_t)s5 * ZPAD + lane] +
         z2[(size_t)s6 * ZPAD + lane] + z2[(size_t)s7 * ZPAD + lane];
  }
  for (; e < end; ++e) a += z2[(size_t)esrc[e] * ZPAD + lane];
  float inv = 1.0f / fmaxf((float)(end - beg), 1.0f);
  if (lane < NCLS)
    out[(size_t)w * NCLS + lane] = s2p[(size_t)w * ZPAD + lane] + a * inv;
}

// ---------------- launch ----------------
extern "C" void kernel_launch(void* const* d_in, const int* in_sizes, int n_in,
                              void* d_out, int out_size, void* d_ws, size_t ws_size,
                              hipStream_t stream) {
  (void)in_sizes; (void)n_in; (void)out_size; (void)ws_size;
  const float* x       = (const float*)d_in[0];
  const int*   src     = (const int*)d_in[1];
  const int*   dst     = (const int*)d_in[2];
  const float* w_self0 = (const float*)d_in[3];
  const float* w_nei0  = (const float*)d_in[4];
  const float* b0      = (const float*)d_in[5];
  const float* g0      = (const float*)d_in[6];
  const float* be0     = (const float*)d_in[7];
  const float* w_self1 = (const float*)d_in[8];
  const float* w_nei1  = (const float*)d_in[9];
  const float* b1      = (const float*)d_in[10];
  const float* g1      = (const float*)d_in[11];
  const float* be1     = (const float*)d_in[12];
  const float* w_self2 = (const float*)d_in[13];
  const float* w_nei2  = (const float*)d_in[14];
  const float* b2      = (const float*)d_in[15];
  float* outp = (float*)d_out;

  char* ws = (char*)d_ws;
  size_t off = 0;
  auto alloc = [&](size_t bytes) -> void* {
    off = (off + 255) & ~(size_t)255;
    void* p = ws + off;
    off += bytes;
    return p;
  };
  int*   counts = (int*)alloc(NN * sizeof(int));
  int*   indptr = (int*)alloc((NN + 1) * sizeof(int));
  int*   cursor = (int*)alloc(NN * sizeof(int));
  int*   bsum   = (int*)alloc(256 * sizeof(int));
  int*   esrc   = (int*)alloc(NE * sizeof(int));
  float* hn     = (float*)alloc((size_t)NN * D * sizeof(float));  // also z2 (layer 2)
  float* h1     = (float*)alloc((size_t)NN * D * sizeof(float));  // also s2p (layer 2)
  float* h2     = (float*)alloc((size_t)NN * D * sizeof(float));
  float* z2  = hn;  // 12.8 MB into 25.6 MB slot
  float* s2p = h1;  // h1 dead once h2 exists

  const int nbScan = (NN + 255) / 256;  // 196

  // CSR build
  hipMemsetAsync(counts, 0, NN * sizeof(int), stream);
  k_count<<<(NE + 255) / 256, 256, 0, stream>>>(dst, counts);
  k_scan1<<<nbScan, 256, 0, stream>>>(counts, indptr, bsum);
  k_scan2<<<1, 256, 0, stream>>>(bsum, nbScan);
  k_scan3<<<nbScan, 256, 0, stream>>>(indptr, bsum, cursor);
  k_scatter<<<(NE + 255) / 256, 256, 0, stream>>>(src, dst, cursor, esrc);

  const int aggBlocks  = (NN * 64) / 256;   // 12500
  const int gemmBlocks = (NN + 31) / 32;    // 1563

  // layer 0
  k_agg<<<aggBlocks, 256, 0, stream>>>(x, indptr, esrc, hn);
  k_gemm_ln<<<gemmBlocks, 256, 0, stream>>>(x, hn, w_self0, w_nei0, b0, g0, be0, h1);
  // layer 1
  k_agg<<<aggBlocks, 256, 0, stream>>>(h1, indptr, esrc, hn);
  k_gemm_ln<<<gemmBlocks, 256, 0, stream>>>(h1, hn, w_self1, w_nei1, b1, g1, be1, h2);
  // layer 2: project first (agg commutes with the linear map), then 64-wide agg
  k_gemm_proj2<<<gemmBlocks, 256, 0, stream>>>(h2, w_self2, w_nei2, b2, s2p, z2);
  k_agg2<<<aggBlocks, 256, 0, stream>>>(z2, s2p, indptr, esrc, outp);
}